// Round 18
// baseline (567.786 us; speedup 1.0000x reference)
//
#include <hip/hip_runtime.h>
#include <math.h>
#include <float.h>

#define NN 50000
#define NE 800000

typedef __attribute__((ext_vector_type(8))) short bf16x8;
typedef __attribute__((ext_vector_type(4))) short bf16x4;
typedef __attribute__((ext_vector_type(2))) short bf16x2;
typedef __attribute__((ext_vector_type(4))) float f32x4;

template<int NC> struct VecT;
template<> struct VecT<2>{ using type = bf16x2; };
template<> struct VecT<4>{ using type = bf16x4; };

__device__ inline short f2bf(float f){
  union { float f; unsigned u; } v; v.f = f;
  unsigned u = v.u + 0x7FFFu + ((v.u >> 16) & 1u);
  return (short)(u >> 16);
}

__device__ inline float bf2f(short b){
  union { unsigned u; float f; } v;
  v.u = ((unsigned)(unsigned short)b) << 16;
  return v.f;
}

// ---------------- setup kernels ----------------

__global__ void k_count(const int* __restrict__ dst, int* __restrict__ cnt){
  int e = blockIdx.x*blockDim.x + threadIdx.x;
  if (e < NE) atomicAdd(&cnt[dst[e]], 1);
}

__global__ void k_scan_part(const int* __restrict__ cnt, int* __restrict__ offs, int* __restrict__ totals){
  __shared__ int sh[1024];
  int t = threadIdx.x, i = blockIdx.x*1024 + t;
  int v = (i < NN) ? cnt[i] : 0;
  sh[t] = v; __syncthreads();
  for (int off = 1; off < 1024; off <<= 1){
    int x = (t >= off) ? sh[t-off] : 0;
    __syncthreads();
    sh[t] += x;
    __syncthreads();
  }
  if (i < NN) offs[i] = sh[t] - v;
  if (t == 1023) totals[blockIdx.x] = sh[t];
}

__global__ void k_scan_tops(int* totals, int nb){
  if (threadIdx.x == 0){
    int acc = 0;
    for (int i = 0; i < nb; i++){ int v = totals[i]; totals[i] = acc; acc += v; }
  }
}

__global__ void k_scan_add(int* __restrict__ offs, const int* __restrict__ totals, int* __restrict__ cursor){
  int i = blockIdx.x*blockDim.x + threadIdx.x;
  if (i < NN){
    int v = offs[i] + totals[i >> 10];
    offs[i] = v;
    cursor[i] = v;
  } else if (i == NN){
    offs[NN] = NE;
  }
}

__global__ void k_scatter(const int* __restrict__ ei, int* __restrict__ cursor,
                          int* __restrict__ ssrc, int* __restrict__ seid){
  int e = blockIdx.x*blockDim.x + threadIdx.x;
  if (e >= NE) return;
  int d = ei[NE + e];
  int p = atomicAdd(&cursor[d], 1);
  ssrc[p] = ei[e];
  seid[p] = e;
}

// thread per edge-slot p: ea_s[p][0..12]=bf16(edge_attr[seid[p]]), [13]=1.0, [14..15]=0
__global__ void k_permute_ea(const float* __restrict__ ea, const int* __restrict__ seid,
                             short* __restrict__ ea_s){
  int p = blockIdx.x*blockDim.x + threadIdx.x;
  if (p >= NE) return;
  int eid = seid[p];
  const float* src = ea + (size_t)eid*13;
  short out[16];
  #pragma unroll
  for (int r = 0; r < 13; r++) out[r] = f2bf(src[r]);
  out[13] = (short)0x3F80;   // bf16(1.0)
  out[14] = 0; out[15] = 0;
  bf16x8* dst = (bf16x8*)(ea_s + (size_t)p*16);
  dst[0] = *(bf16x8*)&out[0];
  dst[1] = *(bf16x8*)&out[8];
}

__global__ void k_sumlog(const int* __restrict__ cnt, float* __restrict__ sumlog){
  __shared__ float sh[256];
  int t = threadIdx.x;
  float s = 0.f;
  for (int i = blockIdx.x*256 + t; i < NN; i += gridDim.x*256)
    s += logf((float)cnt[i] + 1.f);
  sh[t] = s; __syncthreads();
  for (int o = 128; o > 0; o >>= 1){ if (t < o) sh[t] += sh[t+o]; __syncthreads(); }
  if (t == 0) atomicAdd(sumlog, sh[0]);
}

__global__ void k_rscale(const int* __restrict__ cnt, const float* __restrict__ sumlog,
                         float* __restrict__ r1, float* __restrict__ r2){
  int i = blockIdx.x*blockDim.x + threadIdx.x;
  if (i >= NN) return;
  float avg = sumlog[0] / (float)NN;
  float logd = logf(fmaxf((float)cnt[i], 1.f) + 1.f);
  r1[i] = logd / avg;
  r2[i] = avg / logd;
}

// fp32 -> bf16 array convert
__global__ void k_f2bf_arr(const float* __restrict__ in, short* __restrict__ out, int n){
  int i = blockIdx.x*blockDim.x + threadIdx.x;
  if (i < n) out[i] = f2bf(in[i]);
}

// wcT[c][k] = bf16(wc[k][c])
__global__ void k_prep_wcT(const float* __restrict__ wc, short* __restrict__ wcT){
  int idx = blockIdx.x*blockDim.x + threadIdx.x;
  if (idx >= 2560) return;
  int c = idx >> 8, k = idx & 255;
  wcT[idx] = f2bf(wc[k*10 + c]);
}

// BN coefficients: sc = g*rsqrt(var+eps), bc = b - mu*sc   (bnc[0..256)=sc, [256..512)=bc)
__global__ void k_bn_coef(const float* __restrict__ bns, const float* __restrict__ g,
                          const float* __restrict__ b, float* __restrict__ bnc, int fo){
  int c = threadIdx.x;
  if (c >= fo) return;
  float mu = bns[c] / (float)NN;
  float var = bns[fo + c] / (float)NN - mu*mu;
  float sc = g[c] * rsqrtf(var + 1e-5f);
  bnc[c] = sc;
  bnc[256 + c] = b[c] - mu*sc;
}

// ---------------- WolT via MFMA: C[k][o] = wo@wl, stored transposed --------
__global__ __launch_bounds__(256) void k_prep_wol(int K13, int fo,
    const float* __restrict__ wo, const float* __restrict__ wl,
    short* __restrict__ WolT)
{
  __shared__ short As[64*40];
  __shared__ short Bs[64*40];
  int tid = threadIdx.x;
  int lane = tid & 63, w = tid >> 6;
  int wr = w >> 1, wc = w & 1;
  int l15 = lane & 15, l16 = lane >> 4;
  int row0 = blockIdx.x*64, col0 = blockIdx.y*64;
  int sr = tid >> 2, sq = tid & 3;
  f32x4 acc[2][2] = {};
  for (int k0 = 0; k0 < fo; k0 += 32){
    int gr = row0 + sr;                  // k index
    bf16x8 av = {0,0,0,0,0,0,0,0};
    if (gr < K13){
      const float4* src = (const float4*)(wo + (size_t)gr*fo + k0 + sq*8);
      float4 f0 = src[0], f1 = src[1];
      av[0]=f2bf(f0.x); av[1]=f2bf(f0.y); av[2]=f2bf(f0.z); av[3]=f2bf(f0.w);
      av[4]=f2bf(f1.x); av[5]=f2bf(f1.y); av[6]=f2bf(f1.z); av[7]=f2bf(f1.w);
    }
    *(bf16x8*)&As[sr*40 + sq*8] = av;
    int gc = col0 + sr;                  // o index
    bf16x8 bv;
    #pragma unroll
    for (int e = 0; e < 8; e++)
      bv[e] = f2bf(wl[(size_t)(k0 + sq*8 + e)*fo + gc]);
    *(bf16x8*)&Bs[sr*40 + sq*8] = bv;
    __syncthreads();
    bf16x8 af[2], bg[2];
    #pragma unroll
    for (int m = 0; m < 2; m++) af[m] = *(bf16x8*)&As[(wr*32 + m*16 + l15)*40 + l16*8];
    #pragma unroll
    for (int n = 0; n < 2; n++) bg[n] = *(bf16x8*)&Bs[(wc*32 + n*16 + l15)*40 + l16*8];
    #pragma unroll
    for (int m = 0; m < 2; m++)
      #pragma unroll
      for (int n = 0; n < 2; n++)
        acc[m][n] = __builtin_amdgcn_mfma_f32_16x16x32_bf16(af[m], bg[n], acc[m][n], 0, 0, 0);
    __syncthreads();
  }
  #pragma unroll
  for (int m = 0; m < 2; m++){
    #pragma unroll
    for (int n = 0; n < 2; n++){
      int gcol = col0 + wc*32 + n*16 + l15;          // o
      int grow0 = row0 + wr*32 + m*16 + l16*4;       // k (4 consecutive)
      if (grow0 < K13){
        bf16x4 ov;
        #pragma unroll
        for (int i = 0; i < 4; i++) ov[i] = f2bf(acc[m][n][i]);
        *(bf16x4*)(WolT + (size_t)gcol*K13 + grow0) = ov;
      }
    }
  }
}

// ---------------- fused per-layer prep: WeLT | bL2 | wpT | bns=0 ------------
__global__ void k_prep_layer(const float* __restrict__ we, const float* __restrict__ be,
                             const float* __restrict__ wp, const float* __restrict__ bp,
                             short* __restrict__ WeLT, float* __restrict__ bL2,
                             short* __restrict__ wpT,
                             float* __restrict__ bns, int fi, int NCW){
  int fo = 2*fi;
  int n0 = fi*32;
  int n1 = n0 + 2*fi;
  int n2 = n1 + 2*fi*fi;
  int n3 = n2 + 2*fo;
  int idx = blockIdx.x*blockDim.x + threadIdx.x;
  if (idx < n0){
    int jg = idx >> 5, k = idx & 31;
    int Wd = NCW*16;
    int sub = jg / Wd, j = jg - sub*Wd;
    int f = sub*Wd + NCW*(j & 15) + (j >> 4);
    float s = 0.f;
    if (k < 13){
      const float* wpb = wp + (size_t)2*fi*fi;
      const float* wr = we + k*fi;
      for (int jj = 0; jj < fi; jj++) s += wr[jj] * wpb[(size_t)jj*fi + f];
    }
    WeLT[idx] = f2bf(s);
  } else if (idx < n1){
    int f = idx - n0;
    if (f >= fi){ bL2[f] = 0.f; }
    else {
      const float* wpb = wp + (size_t)2*fi*fi;
      float s = bp[f];
      for (int j = 0; j < fi; j++) s += be[j] * wpb[(size_t)j*fi + f];
      bL2[f] = s;
    }
  } else if (idx < n2){
    int id = idx - n1;
    int s = id/(fi*fi), rem = id - s*fi*fi;
    int f = rem/fi, j = rem - f*fi;
    wpT[id] = f2bf(wp[((size_t)s*fi + j)*fi + f]);
  } else if (idx < n3){
    bns[idx - n2] = 0.f;
  }
}

// ---------------- classifier MFMA GEMM (bf16 A + inline-BN, fp32 C) --------
__global__ __launch_bounds__(256) void k_mfma(int M, int Nout, int K,
    const short* __restrict__ A,
    const short* __restrict__ BT, int ldbt,
    float* __restrict__ C, int ldc, const float* __restrict__ bias,
    const float* __restrict__ bnc)
{
  __shared__ short As[64*40];
  __shared__ short Bs[64*40];
  int tid = threadIdx.x;
  int lane = tid & 63, w = tid >> 6;
  int wr = w >> 1, wc = w & 1;
  int l15 = lane & 15, l16 = lane >> 4;
  int row0 = blockIdx.x*64, col0 = blockIdx.y*64;
  int sr = tid >> 2, sq = tid & 3;
  f32x4 acc[2][2] = {};
  for (int k0 = 0; k0 < K; k0 += 32){
    int gr = row0 + sr;
    bf16x8 av = {0,0,0,0,0,0,0,0};
    if (gr < M){
      av = *(const bf16x8*)(A + (size_t)gr*K + k0 + sq*8);
      if (bnc){
        int cb = k0 + sq*8;
        #pragma unroll
        for (int e = 0; e < 8; e++){
          float v = fmaf(bf2f(av[e]), bnc[cb + e], bnc[256 + cb + e]);
          av[e] = f2bf(fmaxf(v, 0.f));
        }
      }
    }
    *(bf16x8*)&As[sr*40 + sq*8] = av;
    int gc = col0 + sr;
    bf16x8 bv = {0,0,0,0,0,0,0,0};
    if (gc < Nout)
      bv = *(const bf16x8*)(BT + (size_t)gc*ldbt + k0 + sq*8);
    *(bf16x8*)&Bs[sr*40 + sq*8] = bv;
    __syncthreads();
    bf16x8 af[2], bg[2];
    #pragma unroll
    for (int m = 0; m < 2; m++) af[m] = *(bf16x8*)&As[(wr*32 + m*16 + l15)*40 + l16*8];
    #pragma unroll
    for (int n = 0; n < 2; n++) bg[n] = *(bf16x8*)&Bs[(wc*32 + n*16 + l15)*40 + l16*8];
    #pragma unroll
    for (int m = 0; m < 2; m++)
      #pragma unroll
      for (int n = 0; n < 2; n++)
        acc[m][n] = __builtin_amdgcn_mfma_f32_16x16x32_bf16(af[m], bg[n], acc[m][n], 0, 0, 0);
    __syncthreads();
  }
  #pragma unroll
  for (int m = 0; m < 2; m++){
    #pragma unroll
    for (int n = 0; n < 2; n++){
      int gcol = col0 + wc*32 + n*16 + l15;
      #pragma unroll
      for (int i = 0; i < 4; i++){
        int grow = row0 + wr*32 + m*16 + l16*4 + i;
        if (grow < M && gcol < Nout)
          C[(size_t)grow*ldc + gcol] = acc[m][n][i] + (bias ? bias[gcol] : 0.f);
      }
    }
  }
}

// ---------------- 128-row MFMA GEMM, dbuf; optional inline-BN on A, optional
// BN-stats epilogue (bns != null), optional bias; bf16 C. Serves both the
// T-GEMM (bias=bL2, bns=null) and the z-GEMM (bias=null, bns=stats).
template<int MREP, int WCG>
__global__ __launch_bounds__(512) void k_mfma_big(int M, int K, int FI,
    const short* __restrict__ P0, const short* __restrict__ P1,
    const short* __restrict__ P2, const short* __restrict__ P3,
    const short* __restrict__ P4,
    const float* __restrict__ r1, const float* __restrict__ r2,
    const short* __restrict__ BT,
    short* __restrict__ Cb, float* __restrict__ bns,
    const float* __restrict__ bnc, const float* __restrict__ bias)
{
  constexpr int NOUT = WCG*64;
  constexpr int ROWS = (8/WCG)*MREP*16;   // 128
  constexpr int NR = 8/WCG;               // waves per column group
  __shared__ short As[2][ROWS*40];
  __shared__ short Bs[2][NOUT*40];
  const short* Pt[5] = {P0, P1, P2, P3, P4};
  int tid = threadIdx.x;
  int lane = tid & 63, w = tid >> 6;
  int wid_c = w % WCG, wid_r = w / WCG;
  int wrow = wid_r * (MREP*16);
  int wcol = wid_c * 64;
  int l15 = lane & 15, l16 = lane >> 4;
  int row0 = blockIdx.x*ROWS;
  int trowA = tid >> 2, tsegA = tid & 3;     // 128 rows x 4 thr (8 shorts each)
  int trowB = tid >> 1, tsegB = tid & 1;     // 256 rows x 2 thr (16 shorts each)
  int gr = row0 + trowA;
  bool aval = gr < M;
  bool bval = trowB < NOUT;
  const short* bsrc = BT + (size_t)trowB*K + tsegB*16;
  f32x4 acc[MREP][4] = {};
  int nt = K/32;

  bf16x8 a0 = {0,0,0,0,0,0,0,0}, b0 = a0, b1 = a0;
  float sval = 1.f; int smv = 0; int bnk = 0;

  auto LOAD = [&](int t){
    int k0 = t*32;
    int kb = k0 / FI;
    int pi = (kb == 0) ? 0 : ((kb - 1) & 3) + 1;
    smv = (kb == 0) ? 0 : ((kb - 1) >> 2);
    bnk = (kb == 0) ? 1 : 0;
    const short* __restrict__ P = Pt[pi];
    int j0 = k0 - kb*FI + tsegA*8;
    bf16x8 z = {0,0,0,0,0,0,0,0};
    a0 = z; b0 = z; b1 = z;
    sval = 1.f;
    if (aval){
      a0 = *(const bf16x8*)(P + (size_t)gr*FI + j0);
      if (smv) sval = (smv == 1) ? r1[gr] : r2[gr];
      if (bnk && bnc){
        #pragma unroll
        for (int e = 0; e < 8; e++){
          float v = fmaf(bf2f(a0[e]), bnc[j0 + e], bnc[256 + j0 + e]);
          a0[e] = f2bf(fmaxf(v, 0.f));
        }
      }
    }
    if (bval){
      const bf16x8* src = (const bf16x8*)(bsrc + k0);
      b0 = src[0]; b1 = src[1];
    }
  };

  LOAD(0);
  int cur = 0;
  for (int t = 0; t < nt; t++){
    if (smv && aval){
      #pragma unroll
      for (int e = 0; e < 8; e++) a0[e] = f2bf(bf2f(a0[e])*sval);
    }
    *(bf16x8*)&As[cur][trowA*40 + tsegA*8] = a0;
    if (bval){
      *(bf16x8*)&Bs[cur][trowB*40 + tsegB*16]     = b0;
      *(bf16x8*)&Bs[cur][trowB*40 + tsegB*16 + 8] = b1;
    }
    __syncthreads();
    if (t + 1 < nt) LOAD(t + 1);
    bf16x8 af[MREP], bg[4];
    #pragma unroll
    for (int m = 0; m < MREP; m++) af[m] = *(bf16x8*)&As[cur][(wrow + m*16 + l15)*40 + l16*8];
    #pragma unroll
    for (int n = 0; n < 4; n++) bg[n] = *(bf16x8*)&Bs[cur][(wcol + n*16 + l15)*40 + l16*8];
    #pragma unroll
    for (int m = 0; m < MREP; m++)
      #pragma unroll
      for (int n = 0; n < 4; n++)
        acc[m][n] = __builtin_amdgcn_mfma_f32_16x16x32_bf16(af[m], bg[n], acc[m][n], 0, 0, 0);
    cur ^= 1;
  }
  // C-store (+bias) + optional per-wave column stats
  float ws[4], ws2[4];
  #pragma unroll
  for (int n = 0; n < 4; n++){
    int gcol = wcol + n*16 + l15;
    float bav = bias ? bias[gcol] : 0.f;
    float s = 0.f, s2 = 0.f;
    #pragma unroll
    for (int m = 0; m < MREP; m++)
      #pragma unroll
      for (int i = 0; i < 4; i++){
        float v = acc[m][n][i] + bav;
        s += v; s2 = fmaf(v, v, s2);
        int grow = row0 + wrow + m*16 + l16*4 + i;
        if (grow < M) Cb[(size_t)grow*NOUT + gcol] = f2bf(v);
      }
    ws[n] = s; ws2[n] = s2;
  }
  if (bns){
    #pragma unroll
    for (int n = 0; n < 4; n++){
      float s = ws[n], s2 = ws2[n];
      s  += __shfl_xor(s, 16, 64);  s  += __shfl_xor(s, 32, 64);
      s2 += __shfl_xor(s2, 16, 64); s2 += __shfl_xor(s2, 32, 64);
      ws[n] = s; ws2[n] = s2;
    }
    float* red = (float*)&As[0][0];        // 8 waves x 128 floats = 4 KB
    __syncthreads();
    if (l16 == 0){
      #pragma unroll
      for (int n = 0; n < 4; n++){
        red[w*128 + n*16 + l15]      = ws[n];
        red[w*128 + 64 + n*16 + l15] = ws2[n];
      }
    }
    __syncthreads();
    if (wid_r == 0 && l16 == 0){
      #pragma unroll
      for (int n = 0; n < 4; n++){
        float ts = 0.f, ts2 = 0.f;
        #pragma unroll
        for (int r = 0; r < NR; r++){
          int ww = r*WCG + wid_c;
          ts  += red[ww*128 + n*16 + l15];
          ts2 += red[ww*128 + 64 + n*16 + l15];
        }
        int gcol = wcol + n*16 + l15;
        atomicAdd(&bns[gcol], ts);
        atomicAdd(&bns[NOUT + gcol], ts2);
      }
    }
  }
}

// ---------------- MFMA aggregation v5: packed + de-masked tail --------------
template<int NC, int FI>   // NC*16 features per wave
__global__ __launch_bounds__(256) void k_agg3(
    const int* __restrict__ offs, const int* __restrict__ ssrc,
    const short* __restrict__ ea_s,      // [NE+16][16] bf16 CSR order, [13]=1.0
    const short* __restrict__ T,         // [NN][2*FI] bf16: [t_d | t_s]
    const short* __restrict__ WeLT,      // logical [FI][32] bf16
    short* __restrict__ mean, short* __restrict__ mn,
    short* __restrict__ mx,  short* __restrict__ stdv)
{
  constexpr int SUBS = FI / (NC*16);
  constexpr int STR = 2*FI;
  using bf16xN = typename VecT<NC>::type;
  const short* t_s = T + FI;
  int wv = (blockIdx.x*blockDim.x + threadIdx.x) >> 6;
  int n = wv / SUBS, sub = wv - n*SUBS;
  if (n >= NN) return;
  int lane = threadIdx.x & 63;
  int l15 = lane & 15, l16 = lane >> 4;
  int c0 = sub * NC * 16;
  bool ins = (l16 == 1);
  bf16xN tdv = *(const bf16xN*)(T + (size_t)n*STR + c0 + NC*l15);
  bf16x8 bfrag[NC];
  #pragma unroll
  for (int c = 0; c < NC; c++){
    bfrag[c] = *(const bf16x8*)(WeLT + (size_t)(c0 + c*16 + l15)*32 + l16*8);
    if (ins) bfrag[c][5] = tdv[c];
  }
  float s[NC], s2[NC], vmn[NC], vmx[NC];
  #pragma unroll
  for (int c = 0; c < NC; c++){ s[c]=0.f; s2[c]=0.f; vmn[c]=FLT_MAX; vmx[c]=-FLT_MAX; }
  int e0 = offs[n], e1 = offs[n+1];
  int p0 = e0;
  int tsoff = c0 + NC*l15;
  // ---- full tiles: no masks ----
  for (; p0 + 16 <= e1; p0 += 16){
    bf16x8 afrag = *(const bf16x8*)(ea_s + (size_t)(p0 + l15)*16 + l16*8);
    bf16xN tsv[4];
    #pragma unroll
    for (int i = 0; i < 4; i++){
      int src = ssrc[p0 + l16*4 + i];
      tsv[i] = *(const bf16xN*)(t_s + (size_t)src*STR + tsoff);
    }
    #pragma unroll
    for (int c = 0; c < NC; c++){
      f32x4 acc = {0.f,0.f,0.f,0.f};
      acc = __builtin_amdgcn_mfma_f32_16x16x32_bf16(afrag, bfrag[c], acc, 0, 0, 0);
      #pragma unroll
      for (int i = 0; i < 4; i++){
        float m = acc[i] + bf2f(tsv[i][c]);
        s[c] += m;
        s2[c] = fmaf(m, m, s2[c]);
        vmn[c] = fminf(vmn[c], m);
        vmx[c] = fmaxf(vmx[c], m);
      }
    }
  }
  // ---- tail tile: OOB slots duplicate edge e1-1 (min/max-safe); s/s2 masked
  if (p0 < e1){
    int pa = p0 + l15; if (pa > e1-1) pa = e1-1;
    bf16x8 afrag = *(const bf16x8*)(ea_s + (size_t)pa*16 + l16*8);
    bf16xN tsv[4]; bool val[4];
    #pragma unroll
    for (int i = 0; i < 4; i++){
      int pp = p0 + l16*4 + i;
      val[i] = pp < e1;
      int pc = val[i] ? pp : (e1-1);
      tsv[i] = *(const bf16xN*)(t_s + (size_t)ssrc[pc]*STR + tsoff);
    }
    #pragma unroll
    for (int c = 0; c < NC; c++){
      f32x4 acc = {0.f,0.f,0.f,0.f};
      acc = __builtin_amdgcn_mfma_f32_16x16x32_bf16(afrag, bfrag[c], acc, 0, 0, 0);
      #pragma unroll
      for (int i = 0; i < 4; i++){
        float m = acc[i] + bf2f(tsv[i][c]);
        float mv = val[i] ? m : 0.f;
        s[c] += mv;
        s2[c] = fmaf(mv, mv, s2[c]);
        vmn[c] = fminf(vmn[c], m);
        vmx[c] = fmaxf(vmx[c], m);
      }
    }
  }
  int cdeg = e1 - e0;
  float denom = fmaxf((float)cdeg, 1.f);
  float rden = 1.0f / denom;
  short* outp = (l16==0) ? mean : (l16==1) ? mn : (l16==2) ? mx : stdv;
  bf16xN ov;
  #pragma unroll
  for (int c = 0; c < NC; c++){
    float sv = s[c];   sv  += __shfl_xor(sv, 16, 64);  sv  += __shfl_xor(sv, 32, 64);
    float s2v = s2[c]; s2v += __shfl_xor(s2v, 16, 64); s2v += __shfl_xor(s2v, 32, 64);
    float mnv = vmn[c]; mnv = fminf(mnv, __shfl_xor(mnv, 16, 64)); mnv = fminf(mnv, __shfl_xor(mnv, 32, 64));
    float mxv = vmx[c]; mxv = fmaxf(mxv, __shfl_xor(mxv, 16, 64)); mxv = fmaxf(mxv, __shfl_xor(mxv, 32, 64));
    float me = sv*rden, me2 = s2v*rden;
    float sd = sqrtf(fmaxf(me2 - me*me, 0.f) + 1e-5f);
    float val = (l16==0) ? me : (l16==1) ? (cdeg>0 ? mnv : 0.f)
              : (l16==2) ? (cdeg>0 ? mxv : 0.f) : sd;
    ov[c] = f2bf(val);
  }
  *(bf16xN*)(outp + (size_t)n*FI + c0 + NC*l15) = ov;
}

// ---------------- host ----------------
extern "C" void kernel_launch(void* const* d_in, const int* in_sizes, int n_in,
                              void* d_out, int out_size, void* d_ws, size_t ws_size,
                              hipStream_t stream){
  const float* x0 = (const float*)d_in[0];
  const int*   ei = (const int*)d_in[1];
  const float* ea = (const float*)d_in[2];
  const float* W[35];
  for (int i = 0; i < 35; i++) W[i] = (const float*)d_in[i];
  const float* wc = W[33];
  const float* bc = W[34];

  char* w = (char*)d_ws;
  auto alloc = [&](size_t bytes)->void*{
    void* p = (void*)w; w += (bytes + 255) & ~(size_t)255; return p;
  };
  int* cnt    = (int*)alloc((size_t)NN*4);
  int* offs   = (int*)alloc((size_t)(NN+1)*4);
  int* cursor = (int*)alloc((size_t)NN*4);
  int* totals = (int*)alloc(64*4);
  int* ssrc   = (int*)alloc((size_t)NE*4);
  int* seid   = (int*)alloc((size_t)NE*4);
  float* sumlog = (float*)alloc(256);
  float* r1   = (float*)alloc((size_t)NN*4);
  float* r2   = (float*)alloc((size_t)NN*4);
  float* bns  = (float*)alloc(512*4);
  float* bnc  = (float*)alloc(3*512*4);               // per-layer BN coefs
  float* bL2  = (float*)alloc(256*4);
  short* WeLT = (short*)alloc((size_t)128*32*2);
  short* WolT = (short*)alloc((size_t)256*1664*2);
  short* wpT  = (short*)alloc((size_t)2*128*128*2);
  short* wcT  = (short*)alloc((size_t)10*256*2);
  short* ea_s = (short*)alloc((size_t)(NE+16)*16*2);  // bf16, CSR-permuted, padded
  short* agg[4];
  for (int a = 0; a < 4; a++) agg[a] = (short*)alloc((size_t)NN*128*2);
  short* FA   = (short*)alloc((size_t)NN*256*2);      // z/activation carriers (bf16)
  short* FB   = (short*)alloc((size_t)NN*256*2);
  short* xbfA = (short*)alloc((size_t)NN*128*2);      // layer-0 input

  hipMemsetAsync(cnt, 0, (size_t)NN*4, stream);
  hipMemsetAsync(sumlog, 0, 4, stream);
  k_count<<<(NE+255)/256, 256, 0, stream>>>(ei + NE, cnt);
  k_scan_part<<<49, 1024, 0, stream>>>(cnt, offs, totals);
  k_scan_tops<<<1, 64, 0, stream>>>(totals, 49);
  k_scan_add<<<(NN+256)/256, 256, 0, stream>>>(offs, totals, cursor);
  k_scatter<<<(NE+255)/256, 256, 0, stream>>>(ei, cursor, ssrc, seid);
  k_permute_ea<<<(NE+255)/256, 256, 0, stream>>>(ea, seid, ea_s);
  k_sumlog<<<256, 256, 0, stream>>>(cnt, sumlog);
  k_rscale<<<(NN+255)/256, 256, 0, stream>>>(cnt, sumlog, r1, r2);
  k_prep_wcT<<<10, 256, 0, stream>>>(wc, wcT);
  k_f2bf_arr<<<(NN*32+255)/256, 256, 0, stream>>>(x0, xbfA, NN*32);

  const short* act = xbfA;
  const float* actBN = nullptr;
  const int fis[3] = {32, 64, 128};
  const int ncws[3] = {2, 2, 2};           // logical packing width (matches agg NC)
  const int GX = (NN + 63) / 64;
  const int GB2 = (NN + 127) / 128;
  for (int l = 0; l < 3; l++){
    int fi = fis[l], fo = 2*fi;
    const float* we = W[3+10*l+0], *be = W[3+10*l+1];
    const float* wp = W[3+10*l+2], *bp = W[3+10*l+3];
    const float* wo = W[3+10*l+4];
    const float* wl = W[3+10*l+6];
    const float* g  = W[3+10*l+8], *bb = W[3+10*l+9];

    short* Fcur = (l & 1) ? FB : FA;         // T then z-out live here
    short* T = Fcur;

    int K13 = 13*fi;
    dim3 gw((K13 + 63)/64, fo/64);
    k_prep_wol<<<gw, 256, 0, stream>>>(K13, fo, wo, wl, WolT);

    int nprep = fi*32 + 2*fi + 2*fi*fi + 2*fo;
    k_prep_layer<<<(nprep+255)/256, 256, 0, stream>>>(we, be, wp, bp,
        WeLT, bL2, wpT, bns, fi, ncws[l]);

    // T-GEMM via pipelined big-tile: Nout = 2*fi, K = fi (FI=K -> kb==0 path)
    if (l == 0)
      k_mfma_big<1,1><<<GB2, 512, 0, stream>>>(NN, fi, fi, act, act, act, act, act,
          r1, r2, wpT, T, nullptr, actBN, bL2);
    else if (l == 1)
      k_mfma_big<2,2><<<GB2, 512, 0, stream>>>(NN, fi, fi, act, act, act, act, act,
          r1, r2, wpT, T, nullptr, actBN, bL2);
    else
      k_mfma_big<4,4><<<GB2, 512, 0, stream>>>(NN, fi, fi, act, act, act, act, act,
          r1, r2, wpT, T, nullptr, actBN, bL2);

    if (l == 0){
      int GA3 = (NN*64 + 255)/256;          // 1 wave/node
      k_agg3<2,32><<<GA3, 256, 0, stream>>>(offs, ssrc, ea_s, T, WeLT,
          agg[0], agg[1], agg[2], agg[3]);
    } else if (l == 1){
      int GA3 = (NN*2*64 + 255)/256;        // 2 waves/node
      k_agg3<2,64><<<GA3, 256, 0, stream>>>(offs, ssrc, ea_s, T, WeLT,
          agg[0], agg[1], agg[2], agg[3]);
    } else {
      int GA3 = (NN*4*64 + 255)/256;        // 4 waves/node
      k_agg3<2,128><<<GA3, 256, 0, stream>>>(offs, ssrc, ea_s, T, WeLT,
          agg[0], agg[1], agg[2], agg[3]);
    }

    if (l == 0)
      k_mfma_big<1,1><<<GB2, 512, 0, stream>>>(NN, 13*fi, fi, act, agg[0], agg[1], agg[2], agg[3],
          r1, r2, WolT, Fcur, bns, actBN, nullptr);
    else if (l == 1)
      k_mfma_big<2,2><<<GB2, 512, 0, stream>>>(NN, 13*fi, fi, act, agg[0], agg[1], agg[2], agg[3],
          r1, r2, WolT, Fcur, bns, actBN, nullptr);
    else
      k_mfma_big<4,4><<<GB2, 512, 0, stream>>>(NN, 13*fi, fi, act, agg[0], agg[1], agg[2], agg[3],
          r1, r2, WolT, Fcur, bns, actBN, nullptr);

    k_bn_coef<<<1, 256, 0, stream>>>(bns, g, bb, bnc + l*512, fo);

    act = Fcur;
    actBN = bnc + l*512;
  }

  dim3 gc(GX, 1);
  k_mfma<<<gc, 256, 0, stream>>>(NN, 10, 256, act, wcT, 256, (float*)d_out, 10, bc, actBN);
}

// Round 19
// 552.865 us; speedup vs baseline: 1.0270x; 1.0270x over previous
//
#include <hip/hip_runtime.h>
#include <math.h>
#include <float.h>

#define NN 50000
#define NE 800000

typedef __attribute__((ext_vector_type(8))) short bf16x8;
typedef __attribute__((ext_vector_type(4))) short bf16x4;
typedef __attribute__((ext_vector_type(2))) short bf16x2;
typedef __attribute__((ext_vector_type(4))) float f32x4;

template<int NC> struct VecT;
template<> struct VecT<2>{ using type = bf16x2; };
template<> struct VecT<4>{ using type = bf16x4; };

__device__ inline short f2bf(float f){
  union { float f; unsigned u; } v; v.f = f;
  unsigned u = v.u + 0x7FFFu + ((v.u >> 16) & 1u);
  return (short)(u >> 16);
}

__device__ inline float bf2f(short b){
  union { unsigned u; float f; } v;
  v.u = ((unsigned)(unsigned short)b) << 16;
  return v.f;
}

// ---------------- setup kernels ----------------

__global__ void k_count(const int* __restrict__ dst, int* __restrict__ cnt){
  int e = blockIdx.x*blockDim.x + threadIdx.x;
  if (e < NE) atomicAdd(&cnt[dst[e]], 1);
}

__global__ void k_scan_part(const int* __restrict__ cnt, int* __restrict__ offs, int* __restrict__ totals){
  __shared__ int sh[1024];
  int t = threadIdx.x, i = blockIdx.x*1024 + t;
  int v = (i < NN) ? cnt[i] : 0;
  sh[t] = v; __syncthreads();
  for (int off = 1; off < 1024; off <<= 1){
    int x = (t >= off) ? sh[t-off] : 0;
    __syncthreads();
    sh[t] += x;
    __syncthreads();
  }
  if (i < NN) offs[i] = sh[t] - v;
  if (t == 1023) totals[blockIdx.x] = sh[t];
}

__global__ void k_scan_tops(int* totals, int nb){
  if (threadIdx.x == 0){
    int acc = 0;
    for (int i = 0; i < nb; i++){ int v = totals[i]; totals[i] = acc; acc += v; }
  }
}

__global__ void k_scan_add(int* __restrict__ offs, const int* __restrict__ totals, int* __restrict__ cursor){
  int i = blockIdx.x*blockDim.x + threadIdx.x;
  if (i < NN){
    int v = offs[i] + totals[i >> 10];
    offs[i] = v;
    cursor[i] = v;
  } else if (i == NN){
    offs[NN] = NE;
  }
}

__global__ void k_scatter(const int* __restrict__ ei, int* __restrict__ cursor,
                          int* __restrict__ ssrc, int* __restrict__ seid){
  int e = blockIdx.x*blockDim.x + threadIdx.x;
  if (e >= NE) return;
  int d = ei[NE + e];
  int p = atomicAdd(&cursor[d], 1);
  ssrc[p] = ei[e];
  seid[p] = e;
}

// thread per edge-slot p: ea_s[p][0..12]=bf16(edge_attr[seid[p]]), [13]=1.0, [14..15]=0
__global__ void k_permute_ea(const float* __restrict__ ea, const int* __restrict__ seid,
                             short* __restrict__ ea_s){
  int p = blockIdx.x*blockDim.x + threadIdx.x;
  if (p >= NE) return;
  int eid = seid[p];
  const float* src = ea + (size_t)eid*13;
  short out[16];
  #pragma unroll
  for (int r = 0; r < 13; r++) out[r] = f2bf(src[r]);
  out[13] = (short)0x3F80;   // bf16(1.0)
  out[14] = 0; out[15] = 0;
  bf16x8* dst = (bf16x8*)(ea_s + (size_t)p*16);
  dst[0] = *(bf16x8*)&out[0];
  dst[1] = *(bf16x8*)&out[8];
}

__global__ void k_sumlog(const int* __restrict__ cnt, float* __restrict__ sumlog){
  __shared__ float sh[256];
  int t = threadIdx.x;
  float s = 0.f;
  for (int i = blockIdx.x*256 + t; i < NN; i += gridDim.x*256)
    s += logf((float)cnt[i] + 1.f);
  sh[t] = s; __syncthreads();
  for (int o = 128; o > 0; o >>= 1){ if (t < o) sh[t] += sh[t+o]; __syncthreads(); }
  if (t == 0) atomicAdd(sumlog, sh[0]);
}

__global__ void k_rscale(const int* __restrict__ cnt, const float* __restrict__ sumlog,
                         float* __restrict__ r1, float* __restrict__ r2){
  int i = blockIdx.x*blockDim.x + threadIdx.x;
  if (i >= NN) return;
  float avg = sumlog[0] / (float)NN;
  float logd = logf(fmaxf((float)cnt[i], 1.f) + 1.f);
  r1[i] = logd / avg;
  r2[i] = avg / logd;
}

// fp32 -> bf16 array convert
__global__ void k_f2bf_arr(const float* __restrict__ in, short* __restrict__ out, int n){
  int i = blockIdx.x*blockDim.x + threadIdx.x;
  if (i < n) out[i] = f2bf(in[i]);
}

// wcT[c][k] = bf16(wc[k][c])
__global__ void k_prep_wcT(const float* __restrict__ wc, short* __restrict__ wcT){
  int idx = blockIdx.x*blockDim.x + threadIdx.x;
  if (idx >= 2560) return;
  int c = idx >> 8, k = idx & 255;
  wcT[idx] = f2bf(wc[k*10 + c]);
}

// BN coefficients: sc = g*rsqrt(var+eps), bc = b - mu*sc   (bnc[0..256)=sc, [256..512)=bc)
__global__ void k_bn_coef(const float* __restrict__ bns, const float* __restrict__ g,
                          const float* __restrict__ b, float* __restrict__ bnc, int fo){
  int c = threadIdx.x;
  if (c >= fo) return;
  float mu = bns[c] / (float)NN;
  float var = bns[fo + c] / (float)NN - mu*mu;
  float sc = g[c] * rsqrtf(var + 1e-5f);
  bnc[c] = sc;
  bnc[256 + c] = b[c] - mu*sc;
}

// ---------------- WolT via MFMA: C[k][o] = wo@wl, stored transposed --------
__global__ __launch_bounds__(256) void k_prep_wol(int K13, int fo,
    const float* __restrict__ wo, const float* __restrict__ wl,
    short* __restrict__ WolT)
{
  __shared__ short As[64*40];
  __shared__ short Bs[64*40];
  int tid = threadIdx.x;
  int lane = tid & 63, w = tid >> 6;
  int wr = w >> 1, wc = w & 1;
  int l15 = lane & 15, l16 = lane >> 4;
  int row0 = blockIdx.x*64, col0 = blockIdx.y*64;
  int sr = tid >> 2, sq = tid & 3;
  f32x4 acc[2][2] = {};
  for (int k0 = 0; k0 < fo; k0 += 32){
    int gr = row0 + sr;                  // k index
    bf16x8 av = {0,0,0,0,0,0,0,0};
    if (gr < K13){
      const float4* src = (const float4*)(wo + (size_t)gr*fo + k0 + sq*8);
      float4 f0 = src[0], f1 = src[1];
      av[0]=f2bf(f0.x); av[1]=f2bf(f0.y); av[2]=f2bf(f0.z); av[3]=f2bf(f0.w);
      av[4]=f2bf(f1.x); av[5]=f2bf(f1.y); av[6]=f2bf(f1.z); av[7]=f2bf(f1.w);
    }
    *(bf16x8*)&As[sr*40 + sq*8] = av;
    int gc = col0 + sr;                  // o index
    bf16x8 bv;
    #pragma unroll
    for (int e = 0; e < 8; e++)
      bv[e] = f2bf(wl[(size_t)(k0 + sq*8 + e)*fo + gc]);
    *(bf16x8*)&Bs[sr*40 + sq*8] = bv;
    __syncthreads();
    bf16x8 af[2], bg[2];
    #pragma unroll
    for (int m = 0; m < 2; m++) af[m] = *(bf16x8*)&As[(wr*32 + m*16 + l15)*40 + l16*8];
    #pragma unroll
    for (int n = 0; n < 2; n++) bg[n] = *(bf16x8*)&Bs[(wc*32 + n*16 + l15)*40 + l16*8];
    #pragma unroll
    for (int m = 0; m < 2; m++)
      #pragma unroll
      for (int n = 0; n < 2; n++)
        acc[m][n] = __builtin_amdgcn_mfma_f32_16x16x32_bf16(af[m], bg[n], acc[m][n], 0, 0, 0);
    __syncthreads();
  }
  #pragma unroll
  for (int m = 0; m < 2; m++){
    #pragma unroll
    for (int n = 0; n < 2; n++){
      int gcol = col0 + wc*32 + n*16 + l15;          // o
      int grow0 = row0 + wr*32 + m*16 + l16*4;       // k (4 consecutive)
      if (grow0 < K13){
        bf16x4 ov;
        #pragma unroll
        for (int i = 0; i < 4; i++) ov[i] = f2bf(acc[m][n][i]);
        *(bf16x4*)(WolT + (size_t)gcol*K13 + grow0) = ov;
      }
    }
  }
}

// ---------------- fused per-layer prep: WeLT | bL2 | wpT | bns=0 ------------
__global__ void k_prep_layer(const float* __restrict__ we, const float* __restrict__ be,
                             const float* __restrict__ wp, const float* __restrict__ bp,
                             short* __restrict__ WeLT, float* __restrict__ bL2,
                             short* __restrict__ wpT,
                             float* __restrict__ bns, int fi, int NCW){
  int fo = 2*fi;
  int n0 = fi*32;
  int n1 = n0 + 2*fi;
  int n2 = n1 + 2*fi*fi;
  int n3 = n2 + 2*fo;
  int idx = blockIdx.x*blockDim.x + threadIdx.x;
  if (idx < n0){
    int jg = idx >> 5, k = idx & 31;
    int Wd = NCW*16;
    int sub = jg / Wd, j = jg - sub*Wd;
    int f = sub*Wd + NCW*(j & 15) + (j >> 4);
    float s = 0.f;
    if (k < 13){
      const float* wpb = wp + (size_t)2*fi*fi;
      const float* wr = we + k*fi;
      for (int jj = 0; jj < fi; jj++) s += wr[jj] * wpb[(size_t)jj*fi + f];
    }
    WeLT[idx] = f2bf(s);
  } else if (idx < n1){
    int f = idx - n0;
    if (f >= fi){ bL2[f] = 0.f; }
    else {
      const float* wpb = wp + (size_t)2*fi*fi;
      float s = bp[f];
      for (int j = 0; j < fi; j++) s += be[j] * wpb[(size_t)j*fi + f];
      bL2[f] = s;
    }
  } else if (idx < n2){
    int id = idx - n1;
    int s = id/(fi*fi), rem = id - s*fi*fi;
    int f = rem/fi, j = rem - f*fi;
    wpT[id] = f2bf(wp[((size_t)s*fi + j)*fi + f]);
  } else if (idx < n3){
    bns[idx - n2] = 0.f;
  }
}

// ---------------- classifier MFMA GEMM (bf16 A + inline-BN, fp32 C) --------
__global__ __launch_bounds__(256) void k_mfma(int M, int Nout, int K,
    const short* __restrict__ A,
    const short* __restrict__ BT, int ldbt,
    float* __restrict__ C, int ldc, const float* __restrict__ bias,
    const float* __restrict__ bnc)
{
  __shared__ short As[64*40];
  __shared__ short Bs[64*40];
  int tid = threadIdx.x;
  int lane = tid & 63, w = tid >> 6;
  int wr = w >> 1, wc = w & 1;
  int l15 = lane & 15, l16 = lane >> 4;
  int row0 = blockIdx.x*64, col0 = blockIdx.y*64;
  int sr = tid >> 2, sq = tid & 3;
  f32x4 acc[2][2] = {};
  for (int k0 = 0; k0 < K; k0 += 32){
    int gr = row0 + sr;
    bf16x8 av = {0,0,0,0,0,0,0,0};
    if (gr < M){
      av = *(const bf16x8*)(A + (size_t)gr*K + k0 + sq*8);
      if (bnc){
        int cb = k0 + sq*8;
        #pragma unroll
        for (int e = 0; e < 8; e++){
          float v = fmaf(bf2f(av[e]), bnc[cb + e], bnc[256 + cb + e]);
          av[e] = f2bf(fmaxf(v, 0.f));
        }
      }
    }
    *(bf16x8*)&As[sr*40 + sq*8] = av;
    int gc = col0 + sr;
    bf16x8 bv = {0,0,0,0,0,0,0,0};
    if (gc < Nout)
      bv = *(const bf16x8*)(BT + (size_t)gc*ldbt + k0 + sq*8);
    *(bf16x8*)&Bs[sr*40 + sq*8] = bv;
    __syncthreads();
    bf16x8 af[2], bg[2];
    #pragma unroll
    for (int m = 0; m < 2; m++) af[m] = *(bf16x8*)&As[(wr*32 + m*16 + l15)*40 + l16*8];
    #pragma unroll
    for (int n = 0; n < 2; n++) bg[n] = *(bf16x8*)&Bs[(wc*32 + n*16 + l15)*40 + l16*8];
    #pragma unroll
    for (int m = 0; m < 2; m++)
      #pragma unroll
      for (int n = 0; n < 2; n++)
        acc[m][n] = __builtin_amdgcn_mfma_f32_16x16x32_bf16(af[m], bg[n], acc[m][n], 0, 0, 0);
    __syncthreads();
  }
  #pragma unroll
  for (int m = 0; m < 2; m++){
    #pragma unroll
    for (int n = 0; n < 2; n++){
      int gcol = col0 + wc*32 + n*16 + l15;
      #pragma unroll
      for (int i = 0; i < 4; i++){
        int grow = row0 + wr*32 + m*16 + l16*4 + i;
        if (grow < M && gcol < Nout)
          C[(size_t)grow*ldc + gcol] = acc[m][n][i] + (bias ? bias[gcol] : 0.f);
      }
    }
  }
}

// ---------------- 128-row MFMA GEMM, dbuf; optional inline-BN on A, optional
// BN-stats epilogue (bns != null), optional bias; bf16 C. Serves both the
// T-GEMM (bias=bL2, bns=null) and the z-GEMM (bias=null, bns=stats).
template<int MREP, int WCG>
__global__ __launch_bounds__(512) void k_mfma_big(int M, int K, int FI,
    const short* __restrict__ P0, const short* __restrict__ P1,
    const short* __restrict__ P2, const short* __restrict__ P3,
    const short* __restrict__ P4,
    const float* __restrict__ r1, const float* __restrict__ r2,
    const short* __restrict__ BT,
    short* __restrict__ Cb, float* __restrict__ bns,
    const float* __restrict__ bnc, const float* __restrict__ bias)
{
  constexpr int NOUT = WCG*64;
  constexpr int ROWS = (8/WCG)*MREP*16;   // 128
  constexpr int NR = 8/WCG;               // waves per column group
  __shared__ short As[2][ROWS*40];
  __shared__ short Bs[2][NOUT*40];
  const short* Pt[5] = {P0, P1, P2, P3, P4};
  int tid = threadIdx.x;
  int lane = tid & 63, w = tid >> 6;
  int wid_c = w % WCG, wid_r = w / WCG;
  int wrow = wid_r * (MREP*16);
  int wcol = wid_c * 64;
  int l15 = lane & 15, l16 = lane >> 4;
  int row0 = blockIdx.x*ROWS;
  int trowA = tid >> 2, tsegA = tid & 3;     // 128 rows x 4 thr (8 shorts each)
  int trowB = tid >> 1, tsegB = tid & 1;     // 256 rows x 2 thr (16 shorts each)
  int gr = row0 + trowA;
  bool aval = gr < M;
  bool bval = trowB < NOUT;
  const short* bsrc = BT + (size_t)trowB*K + tsegB*16;
  f32x4 acc[MREP][4] = {};
  int nt = K/32;

  bf16x8 a0 = {0,0,0,0,0,0,0,0}, b0 = a0, b1 = a0;
  float sval = 1.f; int smv = 0; int bnk = 0;

  auto LOAD = [&](int t){
    int k0 = t*32;
    int kb = k0 / FI;
    int pi = (kb == 0) ? 0 : ((kb - 1) & 3) + 1;
    smv = (kb == 0) ? 0 : ((kb - 1) >> 2);
    bnk = (kb == 0) ? 1 : 0;
    const short* __restrict__ P = Pt[pi];
    int j0 = k0 - kb*FI + tsegA*8;
    bf16x8 z = {0,0,0,0,0,0,0,0};
    a0 = z; b0 = z; b1 = z;
    sval = 1.f;
    if (aval){
      a0 = *(const bf16x8*)(P + (size_t)gr*FI + j0);
      if (smv) sval = (smv == 1) ? r1[gr] : r2[gr];
      if (bnk && bnc){
        #pragma unroll
        for (int e = 0; e < 8; e++){
          float v = fmaf(bf2f(a0[e]), bnc[j0 + e], bnc[256 + j0 + e]);
          a0[e] = f2bf(fmaxf(v, 0.f));
        }
      }
    }
    if (bval){
      const bf16x8* src = (const bf16x8*)(bsrc + k0);
      b0 = src[0]; b1 = src[1];
    }
  };

  LOAD(0);
  int cur = 0;
  for (int t = 0; t < nt; t++){
    if (smv && aval){
      #pragma unroll
      for (int e = 0; e < 8; e++) a0[e] = f2bf(bf2f(a0[e])*sval);
    }
    *(bf16x8*)&As[cur][trowA*40 + tsegA*8] = a0;
    if (bval){
      *(bf16x8*)&Bs[cur][trowB*40 + tsegB*16]     = b0;
      *(bf16x8*)&Bs[cur][trowB*40 + tsegB*16 + 8] = b1;
    }
    __syncthreads();
    if (t + 1 < nt) LOAD(t + 1);
    bf16x8 af[MREP], bg[4];
    #pragma unroll
    for (int m = 0; m < MREP; m++) af[m] = *(bf16x8*)&As[cur][(wrow + m*16 + l15)*40 + l16*8];
    #pragma unroll
    for (int n = 0; n < 4; n++) bg[n] = *(bf16x8*)&Bs[cur][(wcol + n*16 + l15)*40 + l16*8];
    #pragma unroll
    for (int m = 0; m < MREP; m++)
      #pragma unroll
      for (int n = 0; n < 4; n++)
        acc[m][n] = __builtin_amdgcn_mfma_f32_16x16x32_bf16(af[m], bg[n], acc[m][n], 0, 0, 0);
    cur ^= 1;
  }
  // C-store (+bias) + optional per-wave column stats
  float ws[4], ws2[4];
  #pragma unroll
  for (int n = 0; n < 4; n++){
    int gcol = wcol + n*16 + l15;
    float bav = bias ? bias[gcol] : 0.f;
    float s = 0.f, s2 = 0.f;
    #pragma unroll
    for (int m = 0; m < MREP; m++)
      #pragma unroll
      for (int i = 0; i < 4; i++){
        float v = acc[m][n][i] + bav;
        s += v; s2 = fmaf(v, v, s2);
        int grow = row0 + wrow + m*16 + l16*4 + i;
        if (grow < M) Cb[(size_t)grow*NOUT + gcol] = f2bf(v);
      }
    ws[n] = s; ws2[n] = s2;
  }
  if (bns){
    #pragma unroll
    for (int n = 0; n < 4; n++){
      float s = ws[n], s2 = ws2[n];
      s  += __shfl_xor(s, 16, 64);  s  += __shfl_xor(s, 32, 64);
      s2 += __shfl_xor(s2, 16, 64); s2 += __shfl_xor(s2, 32, 64);
      ws[n] = s; ws2[n] = s2;
    }
    float* red = (float*)&As[0][0];        // 8 waves x 128 floats = 4 KB
    __syncthreads();
    if (l16 == 0){
      #pragma unroll
      for (int n = 0; n < 4; n++){
        red[w*128 + n*16 + l15]      = ws[n];
        red[w*128 + 64 + n*16 + l15] = ws2[n];
      }
    }
    __syncthreads();
    if (wid_r == 0 && l16 == 0){
      #pragma unroll
      for (int n = 0; n < 4; n++){
        float ts = 0.f, ts2 = 0.f;
        #pragma unroll
        for (int r = 0; r < NR; r++){
          int ww = r*WCG + wid_c;
          ts  += red[ww*128 + n*16 + l15];
          ts2 += red[ww*128 + 64 + n*16 + l15];
        }
        int gcol = wcol + n*16 + l15;
        atomicAdd(&bns[gcol], ts);
        atomicAdd(&bns[NOUT + gcol], ts2);
      }
    }
  }
}

// ---------------- MFMA aggregation v5: packed + de-masked tail --------------
template<int NC, int FI>   // NC*16 features per wave
__global__ __launch_bounds__(256) void k_agg3(
    const int* __restrict__ offs, const int* __restrict__ ssrc,
    const short* __restrict__ ea_s,      // [NE+16][16] bf16 CSR order, [13]=1.0
    const short* __restrict__ T,         // [NN][2*FI] bf16: [t_d | t_s]
    const short* __restrict__ WeLT,      // logical [FI][32] bf16
    short* __restrict__ mean, short* __restrict__ mn,
    short* __restrict__ mx,  short* __restrict__ stdv)
{
  constexpr int SUBS = FI / (NC*16);
  constexpr int STR = 2*FI;
  using bf16xN = typename VecT<NC>::type;
  const short* t_s = T + FI;
  int wv = (blockIdx.x*blockDim.x + threadIdx.x) >> 6;
  int n = wv / SUBS, sub = wv - n*SUBS;
  if (n >= NN) return;
  int lane = threadIdx.x & 63;
  int l15 = lane & 15, l16 = lane >> 4;
  int c0 = sub * NC * 16;
  bool ins = (l16 == 1);
  bf16xN tdv = *(const bf16xN*)(T + (size_t)n*STR + c0 + NC*l15);
  bf16x8 bfrag[NC];
  #pragma unroll
  for (int c = 0; c < NC; c++){
    bfrag[c] = *(const bf16x8*)(WeLT + (size_t)(c0 + c*16 + l15)*32 + l16*8);
    if (ins) bfrag[c][5] = tdv[c];
  }
  float s[NC], s2[NC], vmn[NC], vmx[NC];
  #pragma unroll
  for (int c = 0; c < NC; c++){ s[c]=0.f; s2[c]=0.f; vmn[c]=FLT_MAX; vmx[c]=-FLT_MAX; }
  int e0 = offs[n], e1 = offs[n+1];
  int p0 = e0;
  int tsoff = c0 + NC*l15;
  // ---- full tiles: no masks ----
  for (; p0 + 16 <= e1; p0 += 16){
    bf16x8 afrag = *(const bf16x8*)(ea_s + (size_t)(p0 + l15)*16 + l16*8);
    bf16xN tsv[4];
    #pragma unroll
    for (int i = 0; i < 4; i++){
      int src = ssrc[p0 + l16*4 + i];
      tsv[i] = *(const bf16xN*)(t_s + (size_t)src*STR + tsoff);
    }
    #pragma unroll
    for (int c = 0; c < NC; c++){
      f32x4 acc = {0.f,0.f,0.f,0.f};
      acc = __builtin_amdgcn_mfma_f32_16x16x32_bf16(afrag, bfrag[c], acc, 0, 0, 0);
      #pragma unroll
      for (int i = 0; i < 4; i++){
        float m = acc[i] + bf2f(tsv[i][c]);
        s[c] += m;
        s2[c] = fmaf(m, m, s2[c]);
        vmn[c] = fminf(vmn[c], m);
        vmx[c] = fmaxf(vmx[c], m);
      }
    }
  }
  // ---- tail tile: OOB slots duplicate edge e1-1 (min/max-safe); s/s2 masked
  if (p0 < e1){
    int pa = p0 + l15; if (pa > e1-1) pa = e1-1;
    bf16x8 afrag = *(const bf16x8*)(ea_s + (size_t)pa*16 + l16*8);
    bf16xN tsv[4]; bool val[4];
    #pragma unroll
    for (int i = 0; i < 4; i++){
      int pp = p0 + l16*4 + i;
      val[i] = pp < e1;
      int pc = val[i] ? pp : (e1-1);
      tsv[i] = *(const bf16xN*)(t_s + (size_t)ssrc[pc]*STR + tsoff);
    }
    #pragma unroll
    for (int c = 0; c < NC; c++){
      f32x4 acc = {0.f,0.f,0.f,0.f};
      acc = __builtin_amdgcn_mfma_f32_16x16x32_bf16(afrag, bfrag[c], acc, 0, 0, 0);
      #pragma unroll
      for (int i = 0; i < 4; i++){
        float m = acc[i] + bf2f(tsv[i][c]);
        float mv = val[i] ? m : 0.f;
        s[c] += mv;
        s2[c] = fmaf(mv, mv, s2[c]);
        vmn[c] = fminf(vmn[c], m);
        vmx[c] = fmaxf(vmx[c], m);
      }
    }
  }
  int cdeg = e1 - e0;
  float denom = fmaxf((float)cdeg, 1.f);
  float rden = 1.0f / denom;
  short* outp = (l16==0) ? mean : (l16==1) ? mn : (l16==2) ? mx : stdv;
  bf16xN ov;
  #pragma unroll
  for (int c = 0; c < NC; c++){
    float sv = s[c];   sv  += __shfl_xor(sv, 16, 64);  sv  += __shfl_xor(sv, 32, 64);
    float s2v = s2[c]; s2v += __shfl_xor(s2v, 16, 64); s2v += __shfl_xor(s2v, 32, 64);
    float mnv = vmn[c]; mnv = fminf(mnv, __shfl_xor(mnv, 16, 64)); mnv = fminf(mnv, __shfl_xor(mnv, 32, 64));
    float mxv = vmx[c]; mxv = fmaxf(mxv, __shfl_xor(mxv, 16, 64)); mxv = fmaxf(mxv, __shfl_xor(mxv, 32, 64));
    float me = sv*rden, me2 = s2v*rden;
    float sd = sqrtf(fmaxf(me2 - me*me, 0.f) + 1e-5f);
    float val = (l16==0) ? me : (l16==1) ? (cdeg>0 ? mnv : 0.f)
              : (l16==2) ? (cdeg>0 ? mxv : 0.f) : sd;
    ov[c] = f2bf(val);
  }
  *(bf16xN*)(outp + (size_t)n*FI + c0 + NC*l15) = ov;
}

// ---------------- host ----------------
extern "C" void kernel_launch(void* const* d_in, const int* in_sizes, int n_in,
                              void* d_out, int out_size, void* d_ws, size_t ws_size,
                              hipStream_t stream){
  const float* x0 = (const float*)d_in[0];
  const int*   ei = (const int*)d_in[1];
  const float* ea = (const float*)d_in[2];
  const float* W[35];
  for (int i = 0; i < 35; i++) W[i] = (const float*)d_in[i];
  const float* wc = W[33];
  const float* bc = W[34];

  char* w = (char*)d_ws;
  auto alloc = [&](size_t bytes)->void*{
    void* p = (void*)w; w += (bytes + 255) & ~(size_t)255; return p;
  };
  int* cnt    = (int*)alloc((size_t)NN*4);
  int* offs   = (int*)alloc((size_t)(NN+1)*4);
  int* cursor = (int*)alloc((size_t)NN*4);
  int* totals = (int*)alloc(64*4);
  int* ssrc   = (int*)alloc((size_t)NE*4);
  int* seid   = (int*)alloc((size_t)NE*4);
  float* sumlog = (float*)alloc(256);
  float* r1   = (float*)alloc((size_t)NN*4);
  float* r2   = (float*)alloc((size_t)NN*4);
  float* bns  = (float*)alloc(512*4);
  float* bnc  = (float*)alloc(3*512*4);               // per-layer BN coefs
  float* bL2  = (float*)alloc(256*4);
  short* WeLT = (short*)alloc((size_t)128*32*2);
  short* WolT = (short*)alloc((size_t)256*1664*2);
  short* wpT  = (short*)alloc((size_t)2*128*128*2);
  short* wcT  = (short*)alloc((size_t)10*256*2);
  short* ea_s = (short*)alloc((size_t)(NE+16)*16*2);  // bf16, CSR-permuted, padded
  short* agg[4];
  for (int a = 0; a < 4; a++) agg[a] = (short*)alloc((size_t)NN*128*2);
  short* FA   = (short*)alloc((size_t)NN*256*2);      // z/activation carriers (bf16)
  short* FB   = (short*)alloc((size_t)NN*256*2);
  short* xbfA = (short*)alloc((size_t)NN*128*2);      // layer-0 input

  hipMemsetAsync(cnt, 0, (size_t)NN*4, stream);
  hipMemsetAsync(sumlog, 0, 4, stream);
  k_count<<<(NE+255)/256, 256, 0, stream>>>(ei + NE, cnt);
  k_scan_part<<<49, 1024, 0, stream>>>(cnt, offs, totals);
  k_scan_tops<<<1, 64, 0, stream>>>(totals, 49);
  k_scan_add<<<(NN+256)/256, 256, 0, stream>>>(offs, totals, cursor);
  k_scatter<<<(NE+255)/256, 256, 0, stream>>>(ei, cursor, ssrc, seid);
  k_permute_ea<<<(NE+255)/256, 256, 0, stream>>>(ea, seid, ea_s);
  k_sumlog<<<256, 256, 0, stream>>>(cnt, sumlog);
  k_rscale<<<(NN+255)/256, 256, 0, stream>>>(cnt, sumlog, r1, r2);
  k_prep_wcT<<<10, 256, 0, stream>>>(wc, wcT);
  k_f2bf_arr<<<(NN*32+255)/256, 256, 0, stream>>>(x0, xbfA, NN*32);

  const short* act = xbfA;
  const float* actBN = nullptr;
  const int fis[3] = {32, 64, 128};
  const int ncws[3] = {2, 4, 4};
  const int GX = (NN + 63) / 64;
  const int GB2 = (NN + 127) / 128;
  for (int l = 0; l < 3; l++){
    int fi = fis[l], fo = 2*fi;
    const float* we = W[3+10*l+0], *be = W[3+10*l+1];
    const float* wp = W[3+10*l+2], *bp = W[3+10*l+3];
    const float* wo = W[3+10*l+4];
    const float* wl = W[3+10*l+6];
    const float* g  = W[3+10*l+8], *bb = W[3+10*l+9];

    short* Fcur = (l & 1) ? FB : FA;         // T then z-out live here
    short* T = Fcur;

    int K13 = 13*fi;
    dim3 gw((K13 + 63)/64, fo/64);
    k_prep_wol<<<gw, 256, 0, stream>>>(K13, fo, wo, wl, WolT);

    int nprep = fi*32 + 2*fi + 2*fi*fi + 2*fo;
    k_prep_layer<<<(nprep+255)/256, 256, 0, stream>>>(we, be, wp, bp,
        WeLT, bL2, wpT, bns, fi, ncws[l]);

    // T-GEMM via pipelined big-tile: Nout = 2*fi, K = fi (FI=K -> kb==0 path)
    if (l == 0)
      k_mfma_big<1,1><<<GB2, 512, 0, stream>>>(NN, fi, fi, act, act, act, act, act,
          r1, r2, wpT, T, nullptr, actBN, bL2);
    else if (l == 1)
      k_mfma_big<2,2><<<GB2, 512, 0, stream>>>(NN, fi, fi, act, act, act, act, act,
          r1, r2, wpT, T, nullptr, actBN, bL2);
    else
      k_mfma_big<4,4><<<GB2, 512, 0, stream>>>(NN, fi, fi, act, act, act, act, act,
          r1, r2, wpT, T, nullptr, actBN, bL2);

    if (l == 0){
      int GA3 = (NN*64 + 255)/256;          // 1 wave/node
      k_agg3<2,32><<<GA3, 256, 0, stream>>>(offs, ssrc, ea_s, T, WeLT,
          agg[0], agg[1], agg[2], agg[3]);
    } else if (l == 1){
      int GA3 = (NN*64 + 255)/256;          // 1 wave/node
      k_agg3<4,64><<<GA3, 256, 0, stream>>>(offs, ssrc, ea_s, T, WeLT,
          agg[0], agg[1], agg[2], agg[3]);
    } else {
      int GA3 = (NN*2*64 + 255)/256;        // 2 waves/node
      k_agg3<4,128><<<GA3, 256, 0, stream>>>(offs, ssrc, ea_s, T, WeLT,
          agg[0], agg[1], agg[2], agg[3]);
    }

    if (l == 0)
      k_mfma_big<1,1><<<GB2, 512, 0, stream>>>(NN, 13*fi, fi, act, agg[0], agg[1], agg[2], agg[3],
          r1, r2, WolT, Fcur, bns, actBN, nullptr);
    else if (l == 1)
      k_mfma_big<2,2><<<GB2, 512, 0, stream>>>(NN, 13*fi, fi, act, agg[0], agg[1], agg[2], agg[3],
          r1, r2, WolT, Fcur, bns, actBN, nullptr);
    else
      k_mfma_big<4,4><<<GB2, 512, 0, stream>>>(NN, 13*fi, fi, act, agg[0], agg[1], agg[2], agg[3],
          r1, r2, WolT, Fcur, bns, actBN, nullptr);

    k_bn_coef<<<1, 256, 0, stream>>>(bns, g, bb, bnc + l*512, fo);

    act = Fcur;
    actBN = bnc + l*512;
  }

  dim3 gc(GX, 1);
  k_mfma<<<gc, 256, 0, stream>>>(NN, 10, 256, act, wcT, 256, (float*)d_out, 10, bc, actBN);
}